// Round 1
// baseline (7338.902 us; speedup 1.0000x reference)
//
#include <hip/hip_runtime.h>
#include <math.h>

#define DD 128      // hidden dim
#define ANND 64     // annotation dim
#define NSTEPS 5
#define NTYPES 4
#define NCLS 10

__device__ __forceinline__ float dot4(float4 a, float4 b) {
  return a.x*b.x + a.y*b.y + a.z*b.z + a.w*b.w;
}

// h[n][d] = d < 64 ? annotation[n][d] : 0
__global__ void k_init_h(const float* __restrict__ ann, float* __restrict__ h, int n) {
  int idx = blockIdx.x * blockDim.x + threadIdx.x;
  if (idx >= n * DD) return;
  int node = idx >> 7, d = idx & 127;
  h[idx] = (d < ANND) ? ann[node * ANND + d] : 0.0f;
}

// out[n][o] = sum_d h[n][d] * W[o][d] + bias[o]      (A @ B^T + b)
// tile: 64 nodes x 128 outputs, 256 threads, K=128 staged in LDS
__global__ __launch_bounds__(256) void k_lin(const float* __restrict__ h,
    const float* __restrict__ W, const float* __restrict__ bias,
    float* __restrict__ out, int n) {
  __shared__ float hs[64 * 132];
  int tid = threadIdx.x;
  int nb = blockIdx.x * 64;
  // stage 64x128 h tile (pad row stride 132 to avoid bank conflicts)
  for (int i = 0; i < 8; ++i) {
    int f4 = tid + i * 256;            // 0..2047
    int row = f4 >> 5, c4 = (f4 & 31) * 4;
    float4 v = make_float4(0.f, 0.f, 0.f, 0.f);
    if (nb + row < n) v = *reinterpret_cast<const float4*>(h + (size_t)(nb + row) * DD + c4);
    *reinterpret_cast<float4*>(hs + row * 132 + c4) = v;
  }
  __syncthreads();
  int tx = tid & 15, ty = tid >> 4;    // tx -> 8 output cols, ty -> 4 rows
  float acc[4][8];
  for (int j = 0; j < 8; ++j) {
    float bv = bias[tx * 8 + j];
    for (int i = 0; i < 4; ++i) acc[i][j] = bv;
  }
  for (int kc = 0; kc < 128; kc += 4) {
    float4 a4[4], w4[8];
    for (int i = 0; i < 4; ++i)
      a4[i] = *reinterpret_cast<const float4*>(hs + (ty * 4 + i) * 132 + kc);
    for (int j = 0; j < 8; ++j)
      w4[j] = *reinterpret_cast<const float4*>(W + (size_t)(tx * 8 + j) * DD + kc);
    for (int i = 0; i < 4; ++i)
      for (int j = 0; j < 8; ++j)
        acc[i][j] += dot4(a4[i], w4[j]);
  }
  for (int i = 0; i < 4; ++i) {
    int node = nb + ty * 4 + i;
    if (node < n) {
      float* o = out + (size_t)node * DD + tx * 8;
      float4 s0 = make_float4(acc[i][0], acc[i][1], acc[i][2], acc[i][3]);
      float4 s1 = make_float4(acc[i][4], acc[i][5], acc[i][6], acc[i][7]);
      *reinterpret_cast<float4*>(o) = s0;
      *reinterpret_cast<float4*>(o + 4) = s1;
    }
  }
}

// a[dst[e]][c] += tmp[src[e]][c] for edges of type ktype
__global__ void k_scatter(const float* __restrict__ tmp, const int* __restrict__ et,
    const int* __restrict__ src, const int* __restrict__ dst,
    float* __restrict__ a, int total, int ktype) {
  int idx = blockIdx.x * blockDim.x + threadIdx.x;
  int stride = gridDim.x * blockDim.x;
  for (; idx < total; idx += stride) {
    int e = idx >> 7, c = idx & 127;
    if (et[e] == ktype)
      atomicAdd(a + (size_t)dst[e] * DD + c, tmp[(size_t)src[e] * DD + c]);
  }
}

// fused GRU: gi = a@W_ih^T + b_ih ; gh = h@W_hh^T + b_hh ; gate math; h updated in place
// block: 512 threads, 32 nodes; thread = (d = tid&127, nl = tid>>7), 8 nodes each
__global__ __launch_bounds__(512) void k_gru(const float* __restrict__ a,
    float* __restrict__ h, const float* __restrict__ Wih, const float* __restrict__ Whh,
    const float* __restrict__ bih, const float* __restrict__ bhh, int n) {
  __shared__ float as[32 * 132];
  __shared__ float hs[32 * 132];
  int tid = threadIdx.x;
  int nb = blockIdx.x * 32;
  for (int i = 0; i < 2; ++i) {
    int f4 = tid + i * 512;            // 0..1023 (32 rows x 32 float4)
    int row = f4 >> 5, c4 = (f4 & 31) * 4;
    float4 va = make_float4(0.f, 0.f, 0.f, 0.f), vh = va;
    if (nb + row < n) {
      va = *reinterpret_cast<const float4*>(a + (size_t)(nb + row) * DD + c4);
      vh = *reinterpret_cast<const float4*>(h + (size_t)(nb + row) * DD + c4);
    }
    *reinterpret_cast<float4*>(as + row * 132 + c4) = va;
    *reinterpret_cast<float4*>(hs + row * 132 + c4) = vh;
  }
  __syncthreads();
  int d = tid & 127, nl = tid >> 7;    // nl in 0..3
  float gir[8], giz[8], gin[8], ghr[8], ghz[8], ghn[8];
  {
    float bir = bih[d], biz = bih[128 + d], bin = bih[256 + d];
    float bhr = bhh[d], bhz = bhh[128 + d], bhn = bhh[256 + d];
    for (int i = 0; i < 8; ++i) {
      gir[i] = bir; giz[i] = biz; gin[i] = bin;
      ghr[i] = bhr; ghz[i] = bhz; ghn[i] = bhn;
    }
  }
  for (int kc = 0; kc < 128; kc += 4) {
    float4 wir = *reinterpret_cast<const float4*>(Wih + (size_t)d * DD + kc);
    float4 wiz = *reinterpret_cast<const float4*>(Wih + (size_t)(128 + d) * DD + kc);
    float4 win = *reinterpret_cast<const float4*>(Wih + (size_t)(256 + d) * DD + kc);
    float4 whr = *reinterpret_cast<const float4*>(Whh + (size_t)d * DD + kc);
    float4 whz = *reinterpret_cast<const float4*>(Whh + (size_t)(128 + d) * DD + kc);
    float4 whn = *reinterpret_cast<const float4*>(Whh + (size_t)(256 + d) * DD + kc);
    for (int i = 0; i < 8; ++i) {
      int row = nl + i * 4;
      float4 a4 = *reinterpret_cast<const float4*>(as + row * 132 + kc);
      float4 h4 = *reinterpret_cast<const float4*>(hs + row * 132 + kc);
      gir[i] += dot4(a4, wir); giz[i] += dot4(a4, wiz); gin[i] += dot4(a4, win);
      ghr[i] += dot4(h4, whr); ghz[i] += dot4(h4, whz); ghn[i] += dot4(h4, whn);
    }
  }
  for (int i = 0; i < 8; ++i) {
    int row = nl + i * 4;
    int node = nb + row;
    if (node < n) {
      float r = 1.f / (1.f + expf(-(gir[i] + ghr[i])));
      float z = 1.f / (1.f + expf(-(giz[i] + ghz[i])));
      float nt = tanhf(gin[i] + r * ghn[i]);
      float ho = hs[row * 132 + d];
      h[(size_t)node * DD + d] = (1.f - z) * nt + z * ho;
    }
  }
}

// gate[n] = dot([h[n] | ann[n]], gate_w) + gate_b    (one wave per node)
__global__ void k_gate(const float* __restrict__ h, const float* __restrict__ ann,
    const float* __restrict__ gw, const float* __restrict__ gb,
    float* __restrict__ gate, int n) {
  int gt = blockIdx.x * blockDim.x + threadIdx.x;
  int wv = gt >> 6;
  int lane = threadIdx.x & 63;
  if (wv >= n) return;
  float p = h[(size_t)wv * DD + lane] * gw[lane]
          + h[(size_t)wv * DD + 64 + lane] * gw[64 + lane]
          + ann[(size_t)wv * ANND + lane] * gw[128 + lane];
  for (int off = 32; off; off >>= 1) p += __shfl_down(p, off);
  if (lane == 0) gate[wv] = p + gb[0];
}

__global__ void k_bounds(const int* __restrict__ n2g, int* __restrict__ startg,
    int* __restrict__ endg, int n) {
  int i = blockIdx.x * blockDim.x + threadIdx.x;
  if (i >= n) return;
  int g = n2g[i];
  atomicMin(&startg[g], i);
  atomicMax(&endg[g], i + 1);
}

// per-graph segment softmax + attention readout
__global__ __launch_bounds__(256) void k_pool(const float* __restrict__ gate,
    float* __restrict__ ex, const float* __restrict__ h, const float* __restrict__ ann,
    const int* __restrict__ startg, const int* __restrict__ endg,
    float* __restrict__ readout, int n) {
  __shared__ float red[256];
  __shared__ float m_s, den_s;
  int g = blockIdx.x;
  int s = startg[g], e = endg[g];
  int tid = threadIdx.x;
  float m = -1e30f;
  for (int i = s + tid; i < e; i += 256) m = fmaxf(m, gate[i]);
  red[tid] = m; __syncthreads();
  for (int off = 128; off; off >>= 1) {
    if (tid < off) red[tid] = fmaxf(red[tid], red[tid + off]);
    __syncthreads();
  }
  if (tid == 0) m_s = red[0];
  __syncthreads();
  m = m_s;
  float sum = 0.f;
  for (int i = s + tid; i < e; i += 256) {
    float v = expf(gate[i] - m);
    ex[i] = v;
    sum += v;
  }
  red[tid] = sum; __syncthreads();
  for (int off = 128; off; off >>= 1) {
    if (tid < off) red[tid] += red[tid + off];
    __syncthreads();
  }
  if (tid == 0) den_s = red[0];
  __syncthreads();
  float inv = (s < e) ? 1.f / den_s : 0.f;
  for (int d = tid; d < DD + ANND; d += 256) {
    float acc = 0.f;
    for (int i = s; i < e; ++i) {
      float f = (d < DD) ? h[(size_t)i * DD + d] : ann[(size_t)i * ANND + (d - DD)];
      acc += ex[i] * f;
    }
    readout[g * (DD + ANND) + d] = acc * inv;
  }
}

// logits, argmax preds, NLL loss. out[0]=loss, out[1+g]=pred_g (as float)
__global__ void k_logits(const float* __restrict__ readout, const float* __restrict__ ow,
    const float* __restrict__ ob, const int* __restrict__ labels,
    float* __restrict__ out, int B) {
  __shared__ float lsum[64];
  int g = threadIdx.x;
  float loss_c = 0.f;
  if (g < B) {
    float lg[NCLS];
    float mx = -1e30f;
    int best = 0;
    for (int c = 0; c < NCLS; ++c) {
      float acc = ob[c];
      const float* r = readout + g * (DD + ANND);
      const float* w = ow + c * (DD + ANND);
      for (int d = 0; d < DD + ANND; ++d) acc += r[d] * w[d];
      lg[c] = acc;
      if (acc > mx) { mx = acc; best = c; }
    }
    float se = 0.f;
    for (int c = 0; c < NCLS; ++c) se += expf(lg[c] - mx);
    float lse = mx + logf(se);
    loss_c = -(lg[labels[g]] - lse);
    out[1 + g] = (float)best;
  }
  lsum[threadIdx.x] = loss_c;
  __syncthreads();
  for (int off = 32; off; off >>= 1) {
    if (threadIdx.x < off) lsum[threadIdx.x] += lsum[threadIdx.x + off];
    __syncthreads();
  }
  if (threadIdx.x == 0) out[0] = lsum[0] / (float)B;
}

extern "C" void kernel_launch(void* const* d_in, const int* in_sizes, int n_in,
                              void* d_out, int out_size, void* d_ws, size_t ws_size,
                              hipStream_t stream) {
  const float* annotation = (const float*)d_in[0];
  const int*   src        = (const int*)d_in[1];
  const int*   dst        = (const int*)d_in[2];
  const int*   et         = (const int*)d_in[3];
  const int*   n2g        = (const int*)d_in[4];
  const int*   labels     = (const int*)d_in[5];
  const float* W_lin      = (const float*)d_in[6];
  const float* b_lin      = (const float*)d_in[7];
  const float* W_ih       = (const float*)d_in[8];
  const float* W_hh       = (const float*)d_in[9];
  const float* b_ih       = (const float*)d_in[10];
  const float* b_hh       = (const float*)d_in[11];
  const float* gate_w     = (const float*)d_in[12];
  const float* gate_b     = (const float*)d_in[13];
  const float* out_w      = (const float*)d_in[14];
  const float* out_b      = (const float*)d_in[15];

  int N = in_sizes[0] / ANND;
  int E = in_sizes[1];
  int B = in_sizes[5];

  char* ws = (char*)d_ws;
  float* h    = (float*)ws; ws += (size_t)N * DD * 4;
  float* tmp  = (float*)ws; ws += (size_t)N * DD * 4;
  float* a    = (float*)ws; ws += (size_t)N * DD * 4;
  float* gate = (float*)ws; ws += (size_t)N * 4;
  float* ex   = (float*)ws; ws += (size_t)N * 4;
  float* readout = (float*)ws; ws += (size_t)B * (DD + ANND) * 4;
  int* startg = (int*)ws; ws += (size_t)B * 4;
  int* endg   = (int*)ws; ws += (size_t)B * 4;

  k_init_h<<<(N * DD + 255) / 256, 256, 0, stream>>>(annotation, h, N);
  hipMemsetAsync(startg, 0x7f, (size_t)B * 4, stream);
  hipMemsetAsync(endg, 0, (size_t)B * 4, stream);
  k_bounds<<<(N + 255) / 256, 256, 0, stream>>>(n2g, startg, endg, N);

  for (int s = 0; s < NSTEPS; ++s) {
    hipMemsetAsync(a, 0, (size_t)N * DD * 4, stream);
    for (int k = 0; k < NTYPES; ++k) {
      k_lin<<<(N + 63) / 64, 256, 0, stream>>>(
          h, W_lin + (size_t)k * DD * DD, b_lin + (size_t)k * DD, tmp, N);
      k_scatter<<<4096, 256, 0, stream>>>(tmp, et, src, dst, a, E * DD, k);
    }
    k_gru<<<(N + 31) / 32, 512, 0, stream>>>(a, h, W_ih, W_hh, b_ih, b_hh, N);
  }

  k_gate<<<(N * 64 + 255) / 256, 256, 0, stream>>>(h, annotation, gate_w, gate_b, gate, N);
  k_pool<<<B, 256, 0, stream>>>(gate, ex, h, annotation, startg, endg, readout, N);
  k_logits<<<1, 64, 0, stream>>>(readout, out_w, out_b, labels, (float*)d_out, B);
}